// Round 12
// baseline (874.370 us; speedup 1.0000x reference)
//
#include <hip/hip_runtime.h>
#include <math.h>

// B=4, C=128, N=512, T=24, D=2, H=4, hd=32, WS=12, R=17, MLP=512
#define TOK 6291456   // element count of one token buffer (now fp16 halves)

typedef _Float16 half8 __attribute__((ext_vector_type(8)));
typedef _Float16 h8 __attribute__((ext_vector_type(8)));
typedef __attribute__((ext_vector_type(4))) float f32x4;

__device__ __forceinline__ float gelu_exact(float x){
    return 0.5f * x * (1.0f + erff(x * 0.70710678118654752f));
}
__device__ __forceinline__ unsigned short f2h(float f){
    return __builtin_bit_cast(unsigned short, (_Float16)f);
}
__device__ __forceinline__ float h2f(unsigned short s){
    return (float)__builtin_bit_cast(_Float16, s);
}

// ---------------------------------------------------------------------------
// s_mask normalizer (probe first 8704 bytes only; classify u8/i32/f32 layout)
// ---------------------------------------------------------------------------
__global__ void normalize_mask(const unsigned char* __restrict__ raw,
                               unsigned char* __restrict__ outm){
    __shared__ int nz[4];
    if(threadIdx.x < 4) nz[threadIdx.x] = 0;
    __syncthreads();
    for(int i = threadIdx.x; i < 8704; i += 256){
        if(raw[i]) atomicOr(&nz[i & 3], 1);
    }
    __syncthreads();
    int mode; // 0=u8, 1=i32, 2=f32
    if(nz[1] | nz[2] | nz[3]) mode = nz[0] ? 0 : 2;
    else                      mode = 1;
    for(int i = threadIdx.x; i < 8704; i += 256){
        unsigned char v;
        if(mode == 0)      v = (raw[i] != 0);
        else if(mode == 1) v = (raw[4*i] != 0);
        else               v = ((raw[4*i+2] | raw[4*i+3]) != 0);
        outm[i] = v;
    }
}

// sec[m][n] = argmax_r assignment[m][n][r]  (exact one-hot f32)
__global__ void build_sec(const float* __restrict__ assign,
                          unsigned char* __restrict__ sec){
    int id = blockIdx.x * 256 + threadIdx.x;
    if(id >= 512*512) return;
    const float* p = assign + (size_t)id * 17;
    int rr = 0;
    #pragma unroll
    for(int r = 0; r < 17; r++) if(p[r] > 0.5f) rr = r;
    sec[id] = (unsigned char)rr;
}

// ---------------------------------------------------------------------------
// weight prep: convert all 18 weight matrices (f32 [K][N]) to fp16 [N][K].
// ---------------------------------------------------------------------------
__global__ void wprep(const float* __restrict__ qkv, const float* __restrict__ tproj,
                      const float* __restrict__ tff1, const float* __restrict__ tff2,
                      const float* __restrict__ sq,   const float* __restrict__ skv,
                      const float* __restrict__ sproj,const float* __restrict__ sff1,
                      const float* __restrict__ sff2, unsigned short* __restrict__ wt){
    const int base[19] = {0,49152,98304,114688,131072,196608,262144,327680,
                          393216,409600,425984,458752,491520,507904,524288,
                          589824,655360,720896,786432};
    for(int gid = blockIdx.x*256 + threadIdx.x; gid < 786432; gid += gridDim.x*256){
        int seg = 0;
        while(gid >= base[seg+1]) seg++;
        int local = gid - base[seg];
        const float* src; int logK;
        switch(seg >> 1){
            case 0: src = qkv;   logK = 7; break;
            case 1: src = tproj; logK = 7; break;
            case 2: src = tff1;  logK = 7; break;
            case 3: src = tff2;  logK = 9; break;
            case 4: src = sq;    logK = 7; break;
            case 5: src = skv;   logK = 7; break;
            case 6: src = sproj; logK = 7; break;
            case 7: src = sff1;  logK = 7; break;
            default: src = sff2; logK = 9; break;
        }
        int sz = base[seg+1] - base[seg];
        int K = 1 << logK, N = sz >> logK;
        src += (seg & 1) * sz;
        int n = local >> logK, k = local & (K - 1);
        wt[gid] = f2h(src[k*N + n]);
    }
}

// h[(b*N+n)*T+t][c] = fp16( x[b][c][n][t] + pos_emb[t][c] )
__global__ __launch_bounds__(128) void stage0(const float* __restrict__ x,
                                              const float* __restrict__ pos,
                                              unsigned short* __restrict__ h){
    __shared__ float l[128*25];
    int bid = blockIdx.x;
    int b = bid >> 9, n = bid & 511;
    int tid = threadIdx.x;
    const float* xb = x + (size_t)b*1572864 + (size_t)n*24;
    for(int it = 0; it < 24; it++){
        int i = it*128 + tid;
        int c = i / 24, t = i % 24;
        l[c*25 + t] = xb[(size_t)c*12288 + t];
    }
    __syncthreads();
    unsigned short* hb = h + ((size_t)(b*512 + n)) * 24 * 128;
    for(int t = 0; t < 24; t++){
        hb[t*128 + tid] = f2h(l[tid*25 + t] + pos[t*128 + tid]);
    }
}

// E[(b*T+t)*N+n][c] = A[(b*N+n)*T+t][c]  (fp16)
__global__ void t2s(const unsigned short* __restrict__ a,
                    unsigned short* __restrict__ e){
    size_t idx = (size_t)blockIdx.x * 256 + threadIdx.x;
    int c = (int)(idx & 127);
    size_t rest = idx >> 7;
    int n = (int)(rest & 511); rest >>= 9;
    int t = (int)(rest % 24);
    int b = (int)(rest / 24);
    e[idx] = a[(((size_t)(b*512 + n))*24 + t)*128 + c];
}

// out[b][c][n][t] = f32( E[(b*T+t)*N+n][c] )
__global__ __launch_bounds__(128) void finalt(const unsigned short* __restrict__ e,
                                              float* __restrict__ out){
    __shared__ float l[128*25];
    int bid = blockIdx.x;
    int b = bid >> 9, n = bid & 511;
    int tid = threadIdx.x;
    for(int t = 0; t < 24; t++){
        l[tid*25 + t] = h2f(e[(((size_t)(b*24 + t))*512 + n)*128 + tid]);
    }
    __syncthreads();
    float* ob = out + (size_t)b*1572864 + (size_t)n*24;
    for(int it = 0; it < 24; it++){
        int i = it*128 + tid;
        int c = i / 24, t = i % 24;
        ob[(size_t)c*12288 + t] = l[c*25 + t];
    }
}

// ---------------------------------------------------------------------------
// gemm5: zero-LDS direct-fragment GEMM for row-major A [M][K] and
// pre-transposed W [N][K]. Each lane loads its MFMA fragments straight from
// global (16B/lane; 16 rows x 64B per load-instr; W is L2-hot). NO LDS, NO
// barriers -> no per-k-step drain stalls (the killer for K=128 / 4-step
// loops), free inter-wave pipelining. Same MFMA order as gemm4 -> identical
// rounding. 128x128 tile, 4 waves as 2x2, acc[4][4].
// ---------------------------------------------------------------------------
template<bool BIAS, bool GELU, bool RES>
__global__ __launch_bounds__(256) void gemm5(const unsigned short* __restrict__ A,
                                             const unsigned short* __restrict__ Wt,
                                             const float* __restrict__ bias,
                                             const unsigned short* __restrict__ res,
                                             unsigned short* __restrict__ out,
                                             int N, int K){
    const int tid = threadIdx.x;
    const int w = tid >> 6, l = tid & 63;
    const int wr = w >> 1, wc = w & 1;
    const int m0 = blockIdx.y * 128;
    const int n0 = blockIdx.x * 128;
    const int colm = l & 15, rg = l >> 4;

    const unsigned short* ap0 = A  + (size_t)(m0 + wr*64 +  0 + colm)*K + rg*8;
    const unsigned short* ap1 = A  + (size_t)(m0 + wr*64 + 16 + colm)*K + rg*8;
    const unsigned short* ap2 = A  + (size_t)(m0 + wr*64 + 32 + colm)*K + rg*8;
    const unsigned short* ap3 = A  + (size_t)(m0 + wr*64 + 48 + colm)*K + rg*8;
    const unsigned short* bp0 = Wt + (size_t)(n0 + wc*64 +  0 + colm)*K + rg*8;
    const unsigned short* bp1 = Wt + (size_t)(n0 + wc*64 + 16 + colm)*K + rg*8;
    const unsigned short* bp2 = Wt + (size_t)(n0 + wc*64 + 32 + colm)*K + rg*8;
    const unsigned short* bp3 = Wt + (size_t)(n0 + wc*64 + 48 + colm)*K + rg*8;

    f32x4 acc[4][4];
    #pragma unroll
    for(int i = 0; i < 4; i++)
        #pragma unroll
        for(int j = 0; j < 4; j++) acc[i][j] = (f32x4){0.f,0.f,0.f,0.f};

    for(int k0 = 0; k0 < K; k0 += 32){
        half8 fa[4], fb[4];
        fa[0] = *(const half8*)ap0; ap0 += 32;
        fa[1] = *(const half8*)ap1; ap1 += 32;
        fa[2] = *(const half8*)ap2; ap2 += 32;
        fa[3] = *(const half8*)ap3; ap3 += 32;
        fb[0] = *(const half8*)bp0; bp0 += 32;
        fb[1] = *(const half8*)bp1; bp1 += 32;
        fb[2] = *(const half8*)bp2; bp2 += 32;
        fb[3] = *(const half8*)bp3; bp3 += 32;
        #pragma unroll
        for(int i = 0; i < 4; i++)
            #pragma unroll
            for(int j = 0; j < 4; j++)
                acc[i][j] = __builtin_amdgcn_mfma_f32_16x16x32_f16(fa[i], fb[j], acc[i][j], 0, 0, 0);
    }

    // epilogue: C/D layout col=lane&15, row=(lane>>4)*4+reg
    #pragma unroll
    for(int i = 0; i < 4; i++){
        #pragma unroll
        for(int j = 0; j < 4; j++){
            int n = n0 + wc*64 + j*16 + colm;
            float bv = BIAS ? bias[n] : 0.f;
            #pragma unroll
            for(int reg = 0; reg < 4; reg++){
                int m = m0 + wr*64 + i*16 + rg*4 + reg;
                float v = acc[i][j][reg] + bv;
                if(GELU) v = gelu_exact(v);
                if(RES)  v += h2f(res[(size_t)m*N + n]);
                out[(size_t)m*N + n] = f2h(v);
            }
        }
    }
}

#define LDA 40
// ---------------------------------------------------------------------------
// gemm4ln: 128x128-tile GEMM (N=128) + fused residual + LayerNorm epilogue.
// (unchanged from R11 - proven)
// ---------------------------------------------------------------------------
__global__ __launch_bounds__(256) void gemm4ln(const unsigned short* __restrict__ A,
                                               const unsigned short* __restrict__ Wt,
                                               const float* __restrict__ bias,
                                               const unsigned short* __restrict__ res,
                                               unsigned short* __restrict__ vout,
                                               unsigned short* __restrict__ lnout,
                                               const float* __restrict__ g,
                                               const float* __restrict__ bb,
                                               int K){
    __shared__ unsigned short As[128*LDA];
    __shared__ unsigned short Ws[128*LDA];
    __shared__ unsigned short vbuf[128*132];   // stride 132 (8B-aligned rows)
    __shared__ float mrow[128], rrow[128];
    const int N = 128;
    const int tid = threadIdx.x;
    const int w = tid >> 6, l = tid & 63;
    const int wr = w >> 1, wc = w & 1;
    const int m0 = blockIdx.y * 128;
    const int r  = tid >> 2;
    const int kq = (tid & 3) * 8;

    const unsigned short* ap0 = A + (size_t)(m0 + r)*K + kq;
    const unsigned short* ap1 = ap0 + (size_t)64*K;
    const unsigned short* wp0 = Wt + (size_t)r*K + kq;
    const unsigned short* wp1 = wp0 + (size_t)64*K;

    int4 av0 = *(const int4*)(ap0);
    int4 av1 = *(const int4*)(ap1);
    int4 wv0 = *(const int4*)(wp0);
    int4 wv1 = *(const int4*)(wp1);

    f32x4 acc[4][4];
    #pragma unroll
    for(int i = 0; i < 4; i++)
        #pragma unroll
        for(int j = 0; j < 4; j++) acc[i][j] = (f32x4){0.f,0.f,0.f,0.f};

    for(int k0 = 0; k0 < K; k0 += 32){
        __syncthreads();
        *(int4*)(&As[r*LDA + kq])      = av0;
        *(int4*)(&As[(r+64)*LDA + kq]) = av1;
        *(int4*)(&Ws[r*LDA + kq])      = wv0;
        *(int4*)(&Ws[(r+64)*LDA + kq]) = wv1;
        __syncthreads();
        if(k0 + 32 < K){
            ap0 += 32; ap1 += 32; wp0 += 32; wp1 += 32;
            av0 = *(const int4*)(ap0);
            av1 = *(const int4*)(ap1);
            wv0 = *(const int4*)(wp0);
            wv1 = *(const int4*)(wp1);
        }
        half8 fa[4], fb[4];
        #pragma unroll
        for(int i = 0; i < 4; i++)
            fa[i] = *(const half8*)(&As[(wr*64 + i*16 + (l & 15))*LDA + (l >> 4)*8]);
        #pragma unroll
        for(int j = 0; j < 4; j++)
            fb[j] = *(const half8*)(&Ws[(wc*64 + j*16 + (l & 15))*LDA + (l >> 4)*8]);
        #pragma unroll
        for(int i = 0; i < 4; i++)
            #pragma unroll
            for(int j = 0; j < 4; j++)
                acc[i][j] = __builtin_amdgcn_mfma_f32_16x16x32_f16(fa[i], fb[j], acc[i][j], 0, 0, 0);
    }

    // phase 1: v = acc + bias + res -> vout + LDS (fp16)
    const int col = l & 15, rg = l >> 4;
    __syncthreads();
    #pragma unroll
    for(int i = 0; i < 4; i++){
        #pragma unroll
        for(int j = 0; j < 4; j++){
            int n = wc*64 + j*16 + col;
            float bv = bias[n];
            #pragma unroll
            for(int reg = 0; reg < 4; reg++){
                int ml_ = wr*64 + i*16 + rg*4 + reg;
                int m = m0 + ml_;
                float v = acc[i][j][reg] + bv + h2f(res[(size_t)m*N + n]);
                unsigned short hv = f2h(v);
                vout[(size_t)m*N + n] = hv;
                vbuf[ml_*132 + n] = hv;
            }
        }
    }
    __syncthreads();

    // phase 2: per-row mean/rstd (thread pair = one row)
    {
        int row = tid >> 1, half = tid & 1;
        float s = 0.f, s2 = 0.f;
        #pragma unroll
        for(int j4 = 0; j4 < 16; j4++){
            unsigned short x4[4] __attribute__((aligned(8)));
            *(uint2*)x4 = *(const uint2*)&vbuf[row*132 + half*64 + j4*4];
            #pragma unroll
            for(int j = 0; j < 4; j++){
                float x = h2f(x4[j]); s += x; s2 += x*x;
            }
        }
        s  += __shfl_xor(s, 1);
        s2 += __shfl_xor(s2, 1);
        if(half == 0){
            float mean = s * (1.0f/128.0f);
            float var  = s2 * (1.0f/128.0f) - mean*mean;
            mrow[row] = mean;
            rrow[row] = rsqrtf(var + 1e-5f);
        }
    }
    __syncthreads();

    // phase 3: coalesced LN transform + write (uint2 = 4 fp16 per store)
    for(int k = 0; k < 16; k++){
        int e4 = tid + k*256;            // 0..4095
        int row = e4 >> 5;
        int c4 = (e4 & 31) * 4;
        unsigned short x4[4] __attribute__((aligned(8)));
        *(uint2*)x4 = *(const uint2*)&vbuf[row*132 + c4];
        float mean = mrow[row], rstd = rrow[row];
        unsigned short o4[4] __attribute__((aligned(8)));
        #pragma unroll
        for(int j = 0; j < 4; j++)
            o4[j] = f2h((h2f(x4[j]) - mean) * rstd * g[c4+j] + bb[c4+j]);
        *(uint2*)&lnout[(size_t)(m0 + row)*128 + c4] = *(const uint2*)o4;
    }
}

// ---------------------------------------------------------------------------
// gemm4kv: skv GEMM (N=256). Block x=0 writes K half; block x=1 writes the V
// half directly transposed to vt[b][ch][n]. (unchanged from R11 - proven)
// ---------------------------------------------------------------------------
__global__ __launch_bounds__(256) void gemm4kv(const unsigned short* __restrict__ A,
                                               const unsigned short* __restrict__ Wt,
                                               unsigned short* __restrict__ out,
                                               unsigned short* __restrict__ vt,
                                               int N, int K){
    __shared__ unsigned short As[128*LDA];
    __shared__ unsigned short Ws[128*LDA];
    const int tid = threadIdx.x;
    const int w = tid >> 6, l = tid & 63;
    const int wr = w >> 1, wc = w & 1;
    const int m0 = blockIdx.y * 128;
    const int n0 = blockIdx.x * 128;
    const int r  = tid >> 2;
    const int kq = (tid & 3) * 8;

    const unsigned short* ap0 = A + (size_t)(m0 + r)*K + kq;
    const unsigned short* ap1 = ap0 + (size_t)64*K;
    const unsigned short* wp0 = Wt + (size_t)(n0 + r)*K + kq;
    const unsigned short* wp1 = wp0 + (size_t)64*K;

    int4 av0 = *(const int4*)(ap0);
    int4 av1 = *(const int4*)(ap1);
    int4 wv0 = *(const int4*)(wp0);
    int4 wv1 = *(const int4*)(wp1);

    f32x4 acc[4][4];
    #pragma unroll
    for(int i = 0; i < 4; i++)
        #pragma unroll
        for(int j = 0; j < 4; j++) acc[i][j] = (f32x4){0.f,0.f,0.f,0.f};

    for(int k0 = 0; k0 < K; k0 += 32){
        __syncthreads();
        *(int4*)(&As[r*LDA + kq])      = av0;
        *(int4*)(&As[(r+64)*LDA + kq]) = av1;
        *(int4*)(&Ws[r*LDA + kq])      = wv0;
        *(int4*)(&Ws[(r+64)*LDA + kq]) = wv1;
        __syncthreads();
        if(k0 + 32 < K){
            ap0 += 32; ap1 += 32; wp0 += 32; wp1 += 32;
            av0 = *(const int4*)(ap0);
            av1 = *(const int4*)(ap1);
            wv0 = *(const int4*)(wp0);
            wv1 = *(const int4*)(wp1);
        }
        half8 fa[4], fb[4];
        #pragma unroll
        for(int i = 0; i < 4; i++)
            fa[i] = *(const half8*)(&As[(wr*64 + i*16 + (l & 15))*LDA + (l >> 4)*8]);
        #pragma unroll
        for(int j = 0; j < 4; j++)
            fb[j] = *(const half8*)(&Ws[(wc*64 + j*16 + (l & 15))*LDA + (l >> 4)*8]);
        #pragma unroll
        for(int i = 0; i < 4; i++)
            #pragma unroll
            for(int j = 0; j < 4; j++)
                acc[i][j] = __builtin_amdgcn_mfma_f32_16x16x32_f16(fa[i], fb[j], acc[i][j], 0, 0, 0);
    }

    const int col = l & 15, rg = l >> 4;
    if(blockIdx.x == 0){
        #pragma unroll
        for(int i = 0; i < 4; i++){
            #pragma unroll
            for(int j = 0; j < 4; j++){
                int n = wc*64 + j*16 + col;
                #pragma unroll
                for(int reg = 0; reg < 4; reg++){
                    int m = m0 + wr*64 + i*16 + rg*4 + reg;
                    out[(size_t)m*N + n] = f2h(acc[i][j][reg]);
                }
            }
        }
    } else {
        #pragma unroll
        for(int i = 0; i < 4; i++){
            #pragma unroll
            for(int j = 0; j < 4; j++){
                int nn = wc*64 + j*16 + col;        // V channel 0..127
                int mbase = m0 + wr*64 + i*16 + rg*4;
                int bl  = mbase >> 9;
                int nsp = mbase & 511;
                unsigned short o4[4] __attribute__((aligned(8)));
                #pragma unroll
                for(int reg = 0; reg < 4; reg++) o4[reg] = f2h(acc[i][j][reg]);
                *(uint2*)(vt + ((size_t)(bl*128 + nn))*512 + nsp) = *(const uint2*)o4;
            }
        }
    }
}

// ---------------------------------------------------------------------------
// temporal windowed causal attention; qkv fp16 rows [q|k|v] 384 wide.
// 4 windows/block (one per wave), 48 active lanes per wave.
// ---------------------------------------------------------------------------
__global__ __launch_bounds__(256) void tattn(const unsigned short* __restrict__ qkv,
                                             unsigned short* __restrict__ out){
    __shared__ unsigned short l[4*12*392];   // 4 windows, rows padded to 392
    int w0 = blockIdx.x * 4;
    const unsigned short* src = qkv + (size_t)w0 * 12 * 384;
    for(int i = threadIdx.x; i < 4608; i += 256){
        int win = i / 1152, rem = i - win*1152;
        int row = rem / 96,  c4  = rem - row*96;
        *(ushort4*)(&l[win*4704 + row*392 + c4*4]) =
            *(const ushort4*)(src + ((size_t)win*12 + row)*384 + c4*4);
    }
    __syncthreads();
    int wv = threadIdx.x >> 6, lane = threadIdx.x & 63;
    if(lane < 48){
        const unsigned short* lw = &l[wv*4704];
        int q = lane % 12, h = lane / 12;
        const float scale = 0.17677669529663687f;
        float qv[32];
        #pragma unroll
        for(int d = 0; d < 32; d++) qv[d] = h2f(lw[q*392 + h*32 + d]);
        float sc[12];
        #pragma unroll
        for(int k = 0; k < 12; k++){
            float dot = 0.f;
            #pragma unroll
            for(int d = 0; d < 32; d++) dot += qv[d] * h2f(lw[k*392 + 128 + h*32 + d]);
            sc[k] = (k <= q) ? dot * scale : -1e30f;
        }
        float mx = sc[0];
        #pragma unroll
        for(int k = 1; k < 12; k++) mx = fmaxf(mx, sc[k]);
        float sum = 0.f;
        #pragma unroll
        for(int k = 0; k < 12; k++){ sc[k] = expf(sc[k] - mx); sum += sc[k]; }
        float inv = 1.0f / sum;
        unsigned short* orow = out + (size_t)((w0 + wv)*12 + q) * 128 + h*32;
        #pragma unroll
        for(int d = 0; d < 32; d++){
            float o = 0.f;
            #pragma unroll
            for(int k = 0; k < 12; k++) o += sc[k] * h2f(lw[k*392 + 256 + h*32 + d]);
            orow[d] = f2h(o * inv);
        }
    }
}

// ---------------------------------------------------------------------------
// sattn2 v9 (unchanged, structural floor ~103us): R7 phase A + packed pairs.
// ---------------------------------------------------------------------------
#define FXS 4096.0f
#define FXI (1.0f/4096.0f)
__global__ __launch_bounds__(256) void sattn2(const unsigned short* __restrict__ qbuf,
                                              const unsigned short* __restrict__ skv,
                                              const unsigned short* __restrict__ vt,
                                              const unsigned char* __restrict__ sec,
                                              const unsigned char* __restrict__ mask,
                                              const float* __restrict__ bias,
                                              unsigned short* __restrict__ out){
    __shared__ unsigned char secl[64*520];   // 64 m rows x 512 sec bytes, stride 520
    __shared__ int logit[64*69];             // fx-int accum; then packed fp16 pairs

    const int cpx = gridDim.x >> 3;          // grid is 8*nb, nb per XCD chunk
    const int sbid = blockIdx.x;
    const int bid = (sbid & 7)*cpx + (sbid >> 3);   // bijective XCD swizzle
    const int b  = bid >> 3;
    const int m0 = (bid & 7) * 64;
    const int tid = threadIdx.x;
    const int w = tid >> 6, l = tid & 63;
    const int colm = l & 15, rg = l >> 4;
    const int ml = w*16 + colm;              // block-local m this lane fragments

    for(int i = tid; i < 4096; i += 256){    // stage sec tile (uint2 = 8 B)
        int row = i >> 6, c8 = i & 63;
        *(uint2*)(&secl[row*520 + c8*8]) =
            *(const uint2*)(sec + (size_t)(m0 + row)*512 + c8*8);
    }
    for(int i = tid; i < 4416; i += 256) logit[i] = 0;
    __syncthreads();

    // ---- phase A: S^T[n][m] = K@Q^T; ds_add_u32 buckets ----
    half8 qf[4];
    #pragma unroll
    for(int h = 0; h < 4; h++)
        qf[h] = *(const half8*)(qbuf + ((size_t)(b*512 + m0 + ml))*128 + h*32 + rg*8);

    for(int cb = 0; cb < 512; cb += 16){
        half8 kf[4];
        #pragma unroll
        for(int h = 0; h < 4; h++)
            kf[h] = *(const half8*)(skv + ((size_t)(b*512 + cb + colm))*256 + h*32 + rg*8);
        unsigned int sdw = *(const unsigned int*)(&secl[ml*520 + cb + rg*4]);
        f32x4 s[4];
        #pragma unroll
        for(int h = 0; h < 4; h++){
            f32x4 z = {0.f,0.f,0.f,0.f};
            s[h] = __builtin_amdgcn_mfma_f32_16x16x32_f16(kf[h], qf[h], z, 0, 0, 0);
        }
        #pragma unroll
        for(int reg = 0; reg < 4; reg++){
            int r = (sdw >> (8*reg)) & 255;
            int* p = &logit[ml*69 + r];
            #pragma unroll
            for(int h = 0; h < 4; h++)
                atomicAdd(p + h*17, __float2int_rn(s[h][reg] * FXS));
        }
    }
    __syncthreads();

    // ---- softmax: thread = (m, head-pair); pack fp16 pairs in place ----
    float p0[17], p1[17];
    int sm_m = 0, sm_hp = 0;
    if(tid < 128){
        sm_m = tid >> 1; sm_hp = tid & 1;
        int gm = m0 + sm_m;
        const float sc17 = 0.17677669529663687f * FXI;
        float mx0 = -1e30f, mx1 = -1e30f;
        int msk[17];
        #pragma unroll
        for(int r = 0; r < 17; r++){
            msk[r] = mask[gm*17 + r];
            p0[r] = (float)logit[sm_m*69 + (sm_hp*2  )*17 + r] * sc17 + bias[(sm_hp*2  )*17 + r];
            p1[r] = (float)logit[sm_m*69 + (sm_hp*2+1)*17 + r] * sc17 + bias[(sm_hp*2+1)*17 + r];
            if(!msk[r]){ mx0 = fmaxf(mx0, p0[r]); mx1 = fmaxf(mx1, p1[r]); }
        }
        float s0 = 0.f, s1 = 0.f;
        #pragma unroll
        for(int r = 0; r < 17; r++){
            float e0 = msk[r] ? 0.f : expf(p0[r] - mx0);
            float e1 = msk[r] ? 0.f : expf(p1[r] - mx1);
            p0[r] = e0; s0 += e0;
            p1[r] = e1; s1 += e1;
        }
        float i0 = 1.0f / s0, i1 = 1.0f / s1;
        #pragma unroll
        for(int r = 0; r < 17; r++){ p0[r] *= i0; p1[r] *= i1; }
    }
    __syncthreads();   // all logit reads complete before in-place overwrite
    if(tid < 128){
        #pragma unroll
        for(int r = 0; r < 17; r++)
            logit[sm_m*69 + sm_hp*17 + r] =
                (int)((unsigned)f2h(p0[r]) | ((unsigned)f2h(p1[r]) << 16));
    }
    __syncthreads();

    // ---- phase B: out[m][ch] = P @ Vt; packed pair = 1 read feeds 2 heads ----
    f32x4 acc[4][2];
    #pragma unroll
    for(int h = 0; h < 4; h++)
        #pragma unroll
        for(int c = 0; c < 2; c++) acc[h][c] = (f32x4){0.f,0.f,0.f,0.f};

    for(int nc = 0; nc < 16; nc++){
        uint2 sd = *(const uint2*)(&secl[ml*520 + nc*32 + rg*8]);
        #pragma unroll
        for(int hp = 0; hp < 2; hp++){
            const unsigned int* apl = (const unsigned int*)&logit[ml*69 + hp*17];
            unsigned short tlo[8] __attribute__((aligned(16)));
            unsigned short thi[8] __attribute__((aligned(16)));
            #pragma unroll
            for(int j = 0; j < 4; j++){
                unsigned v = apl[(sd.x >> (8*j)) & 255];
                tlo[j] = (unsigned short)v; thi[j] = (unsigned short)(v >> 16);
            }
            #pragma unroll
            for(int j = 0; j < 4; j++){
                unsigned v = apl[(sd.y >> (8*j)) & 255];
                tlo[4+j] = (unsigned short)v; thi[4+j] = (unsigned short)(v >> 16);
            }
            half8 pf0 = *(const half8*)tlo;
            half8 pf1 = *(const half8*)thi;
            #pragma unroll
            for(int c = 0; c < 2; c++){
                half8 vf0 = *(const half8*)(vt + ((size_t)(b*128 + (hp*2  )*32 + c*16 + colm))*512
                                               + nc*32 + rg*8);
                half8 vf1 = *(const half8*)(vt + ((size_t)(b*128 + (hp*2+1)*32 + c*16 + colm))*512
                                               + nc*32 + rg*8);
                acc[hp*2  ][c] = __builtin_amdgcn_mfma_f32_16x16x32_f16(pf0, vf0, acc[hp*2  ][c], 0, 0, 0);
                acc[hp*2+1][c] = __builtin_amdgcn_mfma_f32_16x16x32_f16(pf1, vf1, acc[hp*2+1][c], 0, 0, 0);
            }
        }
    }
    #pragma unroll
    for(int h = 0; h < 4; h++)
        #pragma unroll
        for(int c = 0; c < 2; c++)
            #pragma unroll
            for(int reg = 0; reg < 4; reg++)
                out[((size_t)(b*512 + m0 + w*16 + rg*4 + reg))*128 + h*32 + c*16 + colm]
                    = f2h(acc[h][c][reg]);
}

// ---------------------------------------------------------------------------
extern "C" void kernel_launch(void* const* d_in, const int* in_sizes, int n_in,
                              void* d_out, int out_size, void* d_ws, size_t ws_size,
                              hipStream_t stream){
    const float* x        = (const float*)d_in[0];
    const float* pos      = (const float*)d_in[1];
    const float* t_qkv_w  = (const float*)d_in[2];
    const float* t_proj_w = (const float*)d_in[3];
    const float* t_proj_b = (const float*)d_in[4];
    const float* t_ln_g   = (const float*)d_in[5];
    const float* t_ln_b   = (const float*)d_in[6];
    const float* t_ff_w1  = (const float*)d_in[7];
    const float* t_ff_b1  = (const float*)d_in[8];
    const float* t_ff_w2  = (const float*)d_in[9];
    const float* t_ff_b2  = (const float*)d_in[10];
    const float* assign   = (const float*)d_in[11];
    const unsigned char* s_mask_raw = (const unsigned char*)d_in[12];  // dict order!
    const float* s_q_w    = (const float*)d_in[13];
    const float* s_kv_w   = (const float*)d_in[14];
    const float* s_bias   = (const float*)d_in[15];
    const float* s_proj_w = (const float*)d_in[16];
    const float* s_proj_b = (const float*)d_in[17];
    const float* s_ln_g   = (const float*)d_in[18];
    const float* s_ln_b   = (const float*)d_in[19];
    const float* s_ff_w1  = (const float*)d_in[20];
    const float* s_ff_b1  = (const float*)d_in[21];
    const float* s_ff_w2  = (const float*)d_in[22];
    const float* s_ff_b2  = (const float*)d_in[23];

    float* ws = (float*)d_ws;
    // activation buffers are fp16 but keep the float-unit byte offsets
    // (2x over-allocated) to preserve the proven layout.
    const int CH = (ws_size >= (size_t)168*1024*1024) ? 1 : 4;
    unsigned short* A  = (unsigned short*)ws;
    unsigned short* TS = (unsigned short*)(ws + TOK);
    unsigned short* E  = (unsigned short*)((CH==1) ? (ws + 5*(size_t)TOK) : (ws + TOK));
    unsigned short* SS = (CH==1) ? TS : A;
    unsigned short* Cb = (unsigned short*)d_out;  // fp16 scratch inside f32 d_out
    char*  sb = (char*)(ws + ((CH==1)? 6*(size_t)TOK : 2*(size_t)TOK));
    unsigned char*  sec   = (unsigned char*)sb;              // 262144 B
    unsigned char*  maskn = (unsigned char*)(sb + 823296);   // 8704 B
    unsigned short* wt    = (unsigned short*)(sb + 1048576); // 1572864 B fp16 weights

    const int rows = 49152 / CH;       // M rows per chunk (multiple of 128)
    const int nb   = 96 / CH;          // bt values per spatial chunk

    wprep<<<1024, 256, 0, stream>>>(t_qkv_w, t_proj_w, t_ff_w1, t_ff_w2,
                                    s_q_w, s_kv_w, s_proj_w, s_ff_w1, s_ff_w2, wt);
    normalize_mask<<<1, 256, 0, stream>>>(s_mask_raw, maskn);
    build_sec<<<1024, 256, 0, stream>>>(assign, sec);
    stage0<<<2048, 128, 0, stream>>>(x, pos, A);

    for(int d = 0; d < 2; d++){
        for(int c = 0; c < CH; c++){
            const unsigned short* Ac = A + (size_t)c*rows*128;
            gemm5<false,false,false><<<dim3(3, rows/128), 256, 0, stream>>>(
                Ac, wt + d*49152, nullptr, nullptr, TS, 384, 128);
            tattn<<<rows/48, 256, 0, stream>>>(TS, Cb + (size_t)c*rows*128);
        }
        // fused proj + residual + LayerNorm: vout=A, lnout=Cb
        gemm4ln<<<dim3(1, 384), 256, 0, stream>>>(
            Cb, wt + 98304 + d*16384, t_proj_b + d*128, A, A, Cb,
            t_ln_g + d*128, t_ln_b + d*128, 128);
        for(int c = 0; c < CH; c++){
            unsigned short* Ac = A + (size_t)c*rows*128;
            gemm5<true,true,false><<<dim3(4, rows/128), 256, 0, stream>>>(
                Cb + (size_t)c*rows*128, wt + 131072 + d*65536, t_ff_b1 + d*512,
                nullptr, TS, 512, 128);
            gemm5<true,false,true><<<dim3(1, rows/128), 256, 0, stream>>>(
                TS, wt + 262144 + d*65536, t_ff_b2 + d*128, Ac, Ac, 128, 512);
        }
    }

    t2s<<<24576, 256, 0, stream>>>(A, E);

    for(int d = 0; d < 2; d++){
        gemm5<false,false,false><<<dim3(1,384), 256, 0, stream>>>(
            E, wt + 393216 + d*16384, nullptr, nullptr, Cb, 128, 128);
        for(int c = 0; c < CH; c++){
            unsigned short* Ec = E + (size_t)c*nb*512*128;
            unsigned short* skv_u = SS;                              // nb*512*256 fp16
            unsigned short* att = (unsigned short*)((float*)SS + (size_t)nb*512*128);
            unsigned short* vt  = (unsigned short*)((float*)SS + 2*(size_t)nb*512*128);
            gemm4kv<<<dim3(2, nb*512/128), 256, 0, stream>>>(
                Ec, wt + 425984 + d*32768, skv_u, vt, 256, 128);
            sattn2<<<nb*8, 256, 0, stream>>>(
                Cb + (size_t)c*nb*512*128, skv_u, vt, sec, maskn,
                s_bias + d*68, att);
            // fused sproj + residual + LayerNorm: vout=Ec, lnout=Cb chunk
            gemm4ln<<<dim3(1, nb*512/128), 256, 0, stream>>>(
                att, wt + 491520 + d*16384, s_proj_b + d*128, Ec, Ec,
                Cb + (size_t)c*nb*512*128, s_ln_g + d*128, s_ln_b + d*128, 128);
        }
        for(int c = 0; c < CH; c++){
            unsigned short* Ec = E + (size_t)c*rows*128;
            gemm5<true,true,false><<<dim3(4, rows/128), 256, 0, stream>>>(
                Cb + (size_t)c*rows*128, wt + 524288 + d*65536, s_ff_b1 + d*512,
                nullptr, SS, 512, 128);
            gemm5<true,false,true><<<dim3(1, rows/128), 256, 0, stream>>>(
                SS, wt + 655360 + d*65536, s_ff_b2 + d*128, Ec, Ec, 128, 512);
        }
    }

    finalt<<<2048, 128, 0, stream>>>(E, (float*)d_out);
}

// Round 13
// 734.386 us; speedup vs baseline: 1.1906x; 1.1906x over previous
//
#include <hip/hip_runtime.h>
#include <math.h>

// B=4, C=128, N=512, T=24, D=2, H=4, hd=32, WS=12, R=17, MLP=512
#define TOK 6291456   // element count of one token buffer (now fp16 halves)

typedef _Float16 half8 __attribute__((ext_vector_type(8)));
typedef _Float16 h8 __attribute__((ext_vector_type(8)));
typedef __attribute__((ext_vector_type(4))) float f32x4;

__device__ __forceinline__ float gelu_exact(float x){
    return 0.5f * x * (1.0f + erff(x * 0.70710678118654752f));
}
__device__ __forceinline__ unsigned short f2h(float f){
    return __builtin_bit_cast(unsigned short, (_Float16)f);
}
__device__ __forceinline__ float h2f(unsigned short s){
    return (float)__builtin_bit_cast(_Float16, s);
}

// ---------------------------------------------------------------------------
// s_mask normalizer (probe first 8704 bytes only; classify u8/i32/f32 layout)
// ---------------------------------------------------------------------------
__global__ void normalize_mask(const unsigned char* __restrict__ raw,
                               unsigned char* __restrict__ outm){
    __shared__ int nz[4];
    if(threadIdx.x < 4) nz[threadIdx.x] = 0;
    __syncthreads();
    for(int i = threadIdx.x; i < 8704; i += 256){
        if(raw[i]) atomicOr(&nz[i & 3], 1);
    }
    __syncthreads();
    int mode; // 0=u8, 1=i32, 2=f32
    if(nz[1] | nz[2] | nz[3]) mode = nz[0] ? 0 : 2;
    else                      mode = 1;
    for(int i = threadIdx.x; i < 8704; i += 256){
        unsigned char v;
        if(mode == 0)      v = (raw[i] != 0);
        else if(mode == 1) v = (raw[4*i] != 0);
        else               v = ((raw[4*i+2] | raw[4*i+3]) != 0);
        outm[i] = v;
    }
}

// sec[m][n] = argmax_r assignment[m][n][r]  (exact one-hot f32)
__global__ void build_sec(const float* __restrict__ assign,
                          unsigned char* __restrict__ sec){
    int id = blockIdx.x * 256 + threadIdx.x;
    if(id >= 512*512) return;
    const float* p = assign + (size_t)id * 17;
    int rr = 0;
    #pragma unroll
    for(int r = 0; r < 17; r++) if(p[r] > 0.5f) rr = r;
    sec[id] = (unsigned char)rr;
}

// ---------------------------------------------------------------------------
// weight prep: convert all 18 weight matrices (f32 [K][N]) to fp16 [N][K].
// ---------------------------------------------------------------------------
__global__ void wprep(const float* __restrict__ qkv, const float* __restrict__ tproj,
                      const float* __restrict__ tff1, const float* __restrict__ tff2,
                      const float* __restrict__ sq,   const float* __restrict__ skv,
                      const float* __restrict__ sproj,const float* __restrict__ sff1,
                      const float* __restrict__ sff2, unsigned short* __restrict__ wt){
    const int base[19] = {0,49152,98304,114688,131072,196608,262144,327680,
                          393216,409600,425984,458752,491520,507904,524288,
                          589824,655360,720896,786432};
    for(int gid = blockIdx.x*256 + threadIdx.x; gid < 786432; gid += gridDim.x*256){
        int seg = 0;
        while(gid >= base[seg+1]) seg++;
        int local = gid - base[seg];
        const float* src; int logK;
        switch(seg >> 1){
            case 0: src = qkv;   logK = 7; break;
            case 1: src = tproj; logK = 7; break;
            case 2: src = tff1;  logK = 7; break;
            case 3: src = tff2;  logK = 9; break;
            case 4: src = sq;    logK = 7; break;
            case 5: src = skv;   logK = 7; break;
            case 6: src = sproj; logK = 7; break;
            case 7: src = sff1;  logK = 7; break;
            default: src = sff2; logK = 9; break;
        }
        int sz = base[seg+1] - base[seg];
        int K = 1 << logK, N = sz >> logK;
        src += (seg & 1) * sz;
        int n = local >> logK, k = local & (K - 1);
        wt[gid] = f2h(src[k*N + n]);
    }
}

// h[(b*N+n)*T+t][c] = fp16( x[b][c][n][t] + pos_emb[t][c] )
__global__ __launch_bounds__(128) void stage0(const float* __restrict__ x,
                                              const float* __restrict__ pos,
                                              unsigned short* __restrict__ h){
    __shared__ float l[128*25];
    int bid = blockIdx.x;
    int b = bid >> 9, n = bid & 511;
    int tid = threadIdx.x;
    const float* xb = x + (size_t)b*1572864 + (size_t)n*24;
    for(int it = 0; it < 24; it++){
        int i = it*128 + tid;
        int c = i / 24, t = i % 24;
        l[c*25 + t] = xb[(size_t)c*12288 + t];
    }
    __syncthreads();
    unsigned short* hb = h + ((size_t)(b*512 + n)) * 24 * 128;
    for(int t = 0; t < 24; t++){
        hb[t*128 + tid] = f2h(l[tid*25 + t] + pos[t*128 + tid]);
    }
}

// E[(b*T+t)*N+n][c] = A[(b*N+n)*T+t][c]  (fp16)
__global__ void t2s(const unsigned short* __restrict__ a,
                    unsigned short* __restrict__ e){
    size_t idx = (size_t)blockIdx.x * 256 + threadIdx.x;
    int c = (int)(idx & 127);
    size_t rest = idx >> 7;
    int n = (int)(rest & 511); rest >>= 9;
    int t = (int)(rest % 24);
    int b = (int)(rest / 24);
    e[idx] = a[(((size_t)(b*512 + n))*24 + t)*128 + c];
}

// out[b][c][n][t] = f32( E[(b*T+t)*N+n][c] )
__global__ __launch_bounds__(128) void finalt(const unsigned short* __restrict__ e,
                                              float* __restrict__ out){
    __shared__ float l[128*25];
    int bid = blockIdx.x;
    int b = bid >> 9, n = bid & 511;
    int tid = threadIdx.x;
    for(int t = 0; t < 24; t++){
        l[tid*25 + t] = h2f(e[(((size_t)(b*24 + t))*512 + n)*128 + tid]);
    }
    __syncthreads();
    float* ob = out + (size_t)b*1572864 + (size_t)n*24;
    for(int it = 0; it < 24; it++){
        int i = it*128 + tid;
        int c = i / 24, t = i % 24;
        ob[(size_t)c*12288 + t] = l[c*25 + t];
    }
}

#define LDA 40
// ---------------------------------------------------------------------------
// gemm4: 128x128 tile, LDS-staged (the proven workhorse). 4 waves as 2x2;
// each wave owns a 64x64 quadrant (acc[4][4]). Used for ALL plain GEMMs.
// ---------------------------------------------------------------------------
template<bool BIAS, bool GELU, bool RES>
__global__ __launch_bounds__(256) void gemm4(const unsigned short* __restrict__ A,
                                             const unsigned short* __restrict__ Wt,
                                             const float* __restrict__ bias,
                                             const unsigned short* __restrict__ res,
                                             unsigned short* __restrict__ out,
                                             int N, int K){
    __shared__ unsigned short As[128*LDA];
    __shared__ unsigned short Ws[128*LDA];
    const int tid = threadIdx.x;
    const int w = tid >> 6, l = tid & 63;
    const int wr = w >> 1, wc = w & 1;
    const int m0 = blockIdx.y * 128;
    const int n0 = blockIdx.x * 128;
    const int r  = tid >> 2;          // 0..63
    const int kq = (tid & 3) * 8;     // 0,8,16,24

    const unsigned short* ap0 = A + (size_t)(m0 + r)*K + kq;
    const unsigned short* ap1 = ap0 + (size_t)64*K;
    const unsigned short* wp0 = Wt + (size_t)(n0 + r)*K + kq;
    const unsigned short* wp1 = wp0 + (size_t)64*K;

    int4 av0 = *(const int4*)(ap0);
    int4 av1 = *(const int4*)(ap1);
    int4 wv0 = *(const int4*)(wp0);
    int4 wv1 = *(const int4*)(wp1);

    f32x4 acc[4][4];
    #pragma unroll
    for(int i = 0; i < 4; i++)
        #pragma unroll
        for(int j = 0; j < 4; j++) acc[i][j] = (f32x4){0.f,0.f,0.f,0.f};

    for(int k0 = 0; k0 < K; k0 += 32){
        __syncthreads();
        *(int4*)(&As[r*LDA + kq])      = av0;
        *(int4*)(&As[(r+64)*LDA + kq]) = av1;
        *(int4*)(&Ws[r*LDA + kq])      = wv0;
        *(int4*)(&Ws[(r+64)*LDA + kq]) = wv1;
        __syncthreads();
        if(k0 + 32 < K){
            ap0 += 32; ap1 += 32; wp0 += 32; wp1 += 32;
            av0 = *(const int4*)(ap0);
            av1 = *(const int4*)(ap1);
            wv0 = *(const int4*)(wp0);
            wv1 = *(const int4*)(wp1);
        }
        half8 fa[4], fb[4];
        #pragma unroll
        for(int i = 0; i < 4; i++)
            fa[i] = *(const half8*)(&As[(wr*64 + i*16 + (l & 15))*LDA + (l >> 4)*8]);
        #pragma unroll
        for(int j = 0; j < 4; j++)
            fb[j] = *(const half8*)(&Ws[(wc*64 + j*16 + (l & 15))*LDA + (l >> 4)*8]);
        #pragma unroll
        for(int i = 0; i < 4; i++)
            #pragma unroll
            for(int j = 0; j < 4; j++)
                acc[i][j] = __builtin_amdgcn_mfma_f32_16x16x32_f16(fa[i], fb[j], acc[i][j], 0, 0, 0);
    }

    // epilogue: C/D layout col=lane&15, row=(lane>>4)*4+reg
    const int col = l & 15, rg = l >> 4;
    #pragma unroll
    for(int i = 0; i < 4; i++){
        #pragma unroll
        for(int j = 0; j < 4; j++){
            int n = n0 + wc*64 + j*16 + col;
            float bv = BIAS ? bias[n] : 0.f;
            #pragma unroll
            for(int reg = 0; reg < 4; reg++){
                int m = m0 + wr*64 + i*16 + rg*4 + reg;
                float v = acc[i][j][reg] + bv;
                if(GELU) v = gelu_exact(v);
                if(RES)  v += h2f(res[(size_t)m*N + n]);
                out[(size_t)m*N + n] = f2h(v);
            }
        }
    }
}

// ---------------------------------------------------------------------------
// gemm4ln: 128x128-tile GEMM (N=128) + fused residual + LayerNorm epilogue.
// (proven in R11)
// ---------------------------------------------------------------------------
__global__ __launch_bounds__(256) void gemm4ln(const unsigned short* __restrict__ A,
                                               const unsigned short* __restrict__ Wt,
                                               const float* __restrict__ bias,
                                               const unsigned short* __restrict__ res,
                                               unsigned short* __restrict__ vout,
                                               unsigned short* __restrict__ lnout,
                                               const float* __restrict__ g,
                                               const float* __restrict__ bb,
                                               int K){
    __shared__ unsigned short As[128*LDA];
    __shared__ unsigned short Ws[128*LDA];
    __shared__ unsigned short vbuf[128*132];   // stride 132 (8B-aligned rows)
    __shared__ float mrow[128], rrow[128];
    const int N = 128;
    const int tid = threadIdx.x;
    const int w = tid >> 6, l = tid & 63;
    const int wr = w >> 1, wc = w & 1;
    const int m0 = blockIdx.y * 128;
    const int r  = tid >> 2;
    const int kq = (tid & 3) * 8;

    const unsigned short* ap0 = A + (size_t)(m0 + r)*K + kq;
    const unsigned short* ap1 = ap0 + (size_t)64*K;
    const unsigned short* wp0 = Wt + (size_t)r*K + kq;
    const unsigned short* wp1 = wp0 + (size_t)64*K;

    int4 av0 = *(const int4*)(ap0);
    int4 av1 = *(const int4*)(ap1);
    int4 wv0 = *(const int4*)(wp0);
    int4 wv1 = *(const int4*)(wp1);

    f32x4 acc[4][4];
    #pragma unroll
    for(int i = 0; i < 4; i++)
        #pragma unroll
        for(int j = 0; j < 4; j++) acc[i][j] = (f32x4){0.f,0.f,0.f,0.f};

    for(int k0 = 0; k0 < K; k0 += 32){
        __syncthreads();
        *(int4*)(&As[r*LDA + kq])      = av0;
        *(int4*)(&As[(r+64)*LDA + kq]) = av1;
        *(int4*)(&Ws[r*LDA + kq])      = wv0;
        *(int4*)(&Ws[(r+64)*LDA + kq]) = wv1;
        __syncthreads();
        if(k0 + 32 < K){
            ap0 += 32; ap1 += 32; wp0 += 32; wp1 += 32;
            av0 = *(const int4*)(ap0);
            av1 = *(const int4*)(ap1);
            wv0 = *(const int4*)(wp0);
            wv1 = *(const int4*)(wp1);
        }
        half8 fa[4], fb[4];
        #pragma unroll
        for(int i = 0; i < 4; i++)
            fa[i] = *(const half8*)(&As[(wr*64 + i*16 + (l & 15))*LDA + (l >> 4)*8]);
        #pragma unroll
        for(int j = 0; j < 4; j++)
            fb[j] = *(const half8*)(&Ws[(wc*64 + j*16 + (l & 15))*LDA + (l >> 4)*8]);
        #pragma unroll
        for(int i = 0; i < 4; i++)
            #pragma unroll
            for(int j = 0; j < 4; j++)
                acc[i][j] = __builtin_amdgcn_mfma_f32_16x16x32_f16(fa[i], fb[j], acc[i][j], 0, 0, 0);
    }

    // phase 1: v = acc + bias + res -> vout + LDS (fp16)
    const int col = l & 15, rg = l >> 4;
    __syncthreads();
    #pragma unroll
    for(int i = 0; i < 4; i++){
        #pragma unroll
        for(int j = 0; j < 4; j++){
            int n = wc*64 + j*16 + col;
            float bv = bias[n];
            #pragma unroll
            for(int reg = 0; reg < 4; reg++){
                int ml_ = wr*64 + i*16 + rg*4 + reg;
                int m = m0 + ml_;
                float v = acc[i][j][reg] + bv + h2f(res[(size_t)m*N + n]);
                unsigned short hv = f2h(v);
                vout[(size_t)m*N + n] = hv;
                vbuf[ml_*132 + n] = hv;
            }
        }
    }
    __syncthreads();

    // phase 2: per-row mean/rstd (thread pair = one row)
    {
        int row = tid >> 1, half = tid & 1;
        float s = 0.f, s2 = 0.f;
        #pragma unroll
        for(int j4 = 0; j4 < 16; j4++){
            unsigned short x4[4] __attribute__((aligned(8)));
            *(uint2*)x4 = *(const uint2*)&vbuf[row*132 + half*64 + j4*4];
            #pragma unroll
            for(int j = 0; j < 4; j++){
                float x = h2f(x4[j]); s += x; s2 += x*x;
            }
        }
        s  += __shfl_xor(s, 1);
        s2 += __shfl_xor(s2, 1);
        if(half == 0){
            float mean = s * (1.0f/128.0f);
            float var  = s2 * (1.0f/128.0f) - mean*mean;
            mrow[row] = mean;
            rrow[row] = rsqrtf(var + 1e-5f);
        }
    }
    __syncthreads();

    // phase 3: coalesced LN transform + write (uint2 = 4 fp16 per store)
    for(int k = 0; k < 16; k++){
        int e4 = tid + k*256;            // 0..4095
        int row = e4 >> 5;
        int c4 = (e4 & 31) * 4;
        unsigned short x4[4] __attribute__((aligned(8)));
        *(uint2*)x4 = *(const uint2*)&vbuf[row*132 + c4];
        float mean = mrow[row], rstd = rrow[row];
        unsigned short o4[4] __attribute__((aligned(8)));
        #pragma unroll
        for(int j = 0; j < 4; j++)
            o4[j] = f2h((h2f(x4[j]) - mean) * rstd * g[c4+j] + bb[c4+j]);
        *(uint2*)&lnout[(size_t)(m0 + row)*128 + c4] = *(const uint2*)o4;
    }
}

// ---------------------------------------------------------------------------
// gemm4kv: skv GEMM (N=256). Block x=0 writes K half; block x=1 writes the V
// half directly transposed to vt[b][ch][n]. (proven in R11)
// ---------------------------------------------------------------------------
__global__ __launch_bounds__(256) void gemm4kv(const unsigned short* __restrict__ A,
                                               const unsigned short* __restrict__ Wt,
                                               unsigned short* __restrict__ out,
                                               unsigned short* __restrict__ vt,
                                               int N, int K){
    __shared__ unsigned short As[128*LDA];
    __shared__ unsigned short Ws[128*LDA];
    const int tid = threadIdx.x;
    const int w = tid >> 6, l = tid & 63;
    const int wr = w >> 1, wc = w & 1;
    const int m0 = blockIdx.y * 128;
    const int n0 = blockIdx.x * 128;
    const int r  = tid >> 2;
    const int kq = (tid & 3) * 8;

    const unsigned short* ap0 = A + (size_t)(m0 + r)*K + kq;
    const unsigned short* ap1 = ap0 + (size_t)64*K;
    const unsigned short* wp0 = Wt + (size_t)(n0 + r)*K + kq;
    const unsigned short* wp1 = wp0 + (size_t)64*K;

    int4 av0 = *(const int4*)(ap0);
    int4 av1 = *(const int4*)(ap1);
    int4 wv0 = *(const int4*)(wp0);
    int4 wv1 = *(const int4*)(wp1);

    f32x4 acc[4][4];
    #pragma unroll
    for(int i = 0; i < 4; i++)
        #pragma unroll
        for(int j = 0; j < 4; j++) acc[i][j] = (f32x4){0.f,0.f,0.f,0.f};

    for(int k0 = 0; k0 < K; k0 += 32){
        __syncthreads();
        *(int4*)(&As[r*LDA + kq])      = av0;
        *(int4*)(&As[(r+64)*LDA + kq]) = av1;
        *(int4*)(&Ws[r*LDA + kq])      = wv0;
        *(int4*)(&Ws[(r+64)*LDA + kq]) = wv1;
        __syncthreads();
        if(k0 + 32 < K){
            ap0 += 32; ap1 += 32; wp0 += 32; wp1 += 32;
            av0 = *(const int4*)(ap0);
            av1 = *(const int4*)(ap1);
            wv0 = *(const int4*)(wp0);
            wv1 = *(const int4*)(wp1);
        }
        half8 fa[4], fb[4];
        #pragma unroll
        for(int i = 0; i < 4; i++)
            fa[i] = *(const half8*)(&As[(wr*64 + i*16 + (l & 15))*LDA + (l >> 4)*8]);
        #pragma unroll
        for(int j = 0; j < 4; j++)
            fb[j] = *(const half8*)(&Ws[(wc*64 + j*16 + (l & 15))*LDA + (l >> 4)*8]);
        #pragma unroll
        for(int i = 0; i < 4; i++)
            #pragma unroll
            for(int j = 0; j < 4; j++)
                acc[i][j] = __builtin_amdgcn_mfma_f32_16x16x32_f16(fa[i], fb[j], acc[i][j], 0, 0, 0);
    }

    const int col = l & 15, rg = l >> 4;
    if(blockIdx.x == 0){
        #pragma unroll
        for(int i = 0; i < 4; i++){
            #pragma unroll
            for(int j = 0; j < 4; j++){
                int n = wc*64 + j*16 + col;
                #pragma unroll
                for(int reg = 0; reg < 4; reg++){
                    int m = m0 + wr*64 + i*16 + rg*4 + reg;
                    out[(size_t)m*N + n] = f2h(acc[i][j][reg]);
                }
            }
        }
    } else {
        #pragma unroll
        for(int i = 0; i < 4; i++){
            #pragma unroll
            for(int j = 0; j < 4; j++){
                int nn = wc*64 + j*16 + col;        // V channel 0..127
                int mbase = m0 + wr*64 + i*16 + rg*4;
                int bl  = mbase >> 9;
                int nsp = mbase & 511;
                unsigned short o4[4] __attribute__((aligned(8)));
                #pragma unroll
                for(int reg = 0; reg < 4; reg++) o4[reg] = f2h(acc[i][j][reg]);
                *(uint2*)(vt + ((size_t)(bl*128 + nn))*512 + nsp) = *(const uint2*)o4;
            }
        }
    }
}

// ---------------------------------------------------------------------------
// temporal windowed causal attention; qkv fp16 rows [q|k|v] 384 wide.
// 4 windows/block (one per wave), 48 active lanes per wave.
// ---------------------------------------------------------------------------
__global__ __launch_bounds__(256) void tattn(const unsigned short* __restrict__ qkv,
                                             unsigned short* __restrict__ out){
    __shared__ unsigned short l[4*12*392];   // 4 windows, rows padded to 392
    int w0 = blockIdx.x * 4;
    const unsigned short* src = qkv + (size_t)w0 * 12 * 384;
    for(int i = threadIdx.x; i < 4608; i += 256){
        int win = i / 1152, rem = i - win*1152;
        int row = rem / 96,  c4  = rem - row*96;
        *(ushort4*)(&l[win*4704 + row*392 + c4*4]) =
            *(const ushort4*)(src + ((size_t)win*12 + row)*384 + c4*4);
    }
    __syncthreads();
    int wv = threadIdx.x >> 6, lane = threadIdx.x & 63;
    if(lane < 48){
        const unsigned short* lw = &l[wv*4704];
        int q = lane % 12, h = lane / 12;
        const float scale = 0.17677669529663687f;
        float qv[32];
        #pragma unroll
        for(int d = 0; d < 32; d++) qv[d] = h2f(lw[q*392 + h*32 + d]);
        float sc[12];
        #pragma unroll
        for(int k = 0; k < 12; k++){
            float dot = 0.f;
            #pragma unroll
            for(int d = 0; d < 32; d++) dot += qv[d] * h2f(lw[k*392 + 128 + h*32 + d]);
            sc[k] = (k <= q) ? dot * scale : -1e30f;
        }
        float mx = sc[0];
        #pragma unroll
        for(int k = 1; k < 12; k++) mx = fmaxf(mx, sc[k]);
        float sum = 0.f;
        #pragma unroll
        for(int k = 0; k < 12; k++){ sc[k] = expf(sc[k] - mx); sum += sc[k]; }
        float inv = 1.0f / sum;
        unsigned short* orow = out + (size_t)((w0 + wv)*12 + q) * 128 + h*32;
        #pragma unroll
        for(int d = 0; d < 32; d++){
            float o = 0.f;
            #pragma unroll
            for(int k = 0; k < 12; k++) o += sc[k] * h2f(lw[k*392 + 256 + h*32 + d]);
            orow[d] = f2h(o * inv);
        }
    }
}

// ---------------------------------------------------------------------------
// sattn2 v9 (unchanged, structural floor ~103us): R7 phase A + packed pairs.
// ---------------------------------------------------------------------------
#define FXS 4096.0f
#define FXI (1.0f/4096.0f)
__global__ __launch_bounds__(256) void sattn2(const unsigned short* __restrict__ qbuf,
                                              const unsigned short* __restrict__ skv,
                                              const unsigned short* __restrict__ vt,
                                              const unsigned char* __restrict__ sec,
                                              const unsigned char* __restrict__ mask,
                                              const float* __restrict__ bias,
                                              unsigned short* __restrict__ out){
    __shared__ unsigned char secl[64*520];   // 64 m rows x 512 sec bytes, stride 520
    __shared__ int logit[64*69];             // fx-int accum; then packed fp16 pairs

    const int cpx = gridDim.x >> 3;          // grid is 8*nb, nb per XCD chunk
    const int sbid = blockIdx.x;
    const int bid = (sbid & 7)*cpx + (sbid >> 3);   // bijective XCD swizzle
    const int b  = bid >> 3;
    const int m0 = (bid & 7) * 64;
    const int tid = threadIdx.x;
    const int w = tid >> 6, l = tid & 63;
    const int colm = l & 15, rg = l >> 4;
    const int ml = w*16 + colm;              // block-local m this lane fragments

    for(int i = tid; i < 4096; i += 256){    // stage sec tile (uint2 = 8 B)
        int row = i >> 6, c8 = i & 63;
        *(uint2*)(&secl[row*520 + c8*8]) =
            *(const uint2*)(sec + (size_t)(m0 + row)*512 + c8*8);
    }
    for(int i = tid; i < 4416; i += 256) logit[i] = 0;
    __syncthreads();

    // ---- phase A: S^T[n][m] = K@Q^T; ds_add_u32 buckets ----
    half8 qf[4];
    #pragma unroll
    for(int h = 0; h < 4; h++)
        qf[h] = *(const half8*)(qbuf + ((size_t)(b*512 + m0 + ml))*128 + h*32 + rg*8);

    for(int cb = 0; cb < 512; cb += 16){
        half8 kf[4];
        #pragma unroll
        for(int h = 0; h < 4; h++)
            kf[h] = *(const half8*)(skv + ((size_t)(b*512 + cb + colm))*256 + h*32 + rg*8);
        unsigned int sdw = *(const unsigned int*)(&secl[ml*520 + cb + rg*4]);
        f32x4 s[4];
        #pragma unroll
        for(int h = 0; h < 4; h++){
            f32x4 z = {0.f,0.f,0.f,0.f};
            s[h] = __builtin_amdgcn_mfma_f32_16x16x32_f16(kf[h], qf[h], z, 0, 0, 0);
        }
        #pragma unroll
        for(int reg = 0; reg < 4; reg++){
            int r = (sdw >> (8*reg)) & 255;
            int* p = &logit[ml*69 + r];
            #pragma unroll
            for(int h = 0; h < 4; h++)
                atomicAdd(p + h*17, __float2int_rn(s[h][reg] * FXS));
        }
    }
    __syncthreads();

    // ---- softmax: thread = (m, head-pair); pack fp16 pairs in place ----
    float p0[17], p1[17];
    int sm_m = 0, sm_hp = 0;
    if(tid < 128){
        sm_m = tid >> 1; sm_hp = tid & 1;
        int gm = m0 + sm_m;
        const float sc17 = 0.17677669529663687f * FXI;
        float mx0 = -1e30f, mx1 = -1e30f;
        int msk[17];
        #pragma unroll
        for(int r = 0; r < 17; r++){
            msk[r] = mask[gm*17 + r];
            p0[r] = (float)logit[sm_m*69 + (sm_hp*2  )*17 + r] * sc17 + bias[(sm_hp*2  )*17 + r];
            p1[r] = (float)logit[sm_m*69 + (sm_hp*2+1)*17 + r] * sc17 + bias[(sm_hp*2+1)*17 + r];
            if(!msk[r]){ mx0 = fmaxf(mx0, p0[r]); mx1 = fmaxf(mx1, p1[r]); }
        }
        float s0 = 0.f, s1 = 0.f;
        #pragma unroll
        for(int r = 0; r < 17; r++){
            float e0 = msk[r] ? 0.f : expf(p0[r] - mx0);
            float e1 = msk[r] ? 0.f : expf(p1[r] - mx1);
            p0[r] = e0; s0 += e0;
            p1[r] = e1; s1 += e1;
        }
        float i0 = 1.0f / s0, i1 = 1.0f / s1;
        #pragma unroll
        for(int r = 0; r < 17; r++){ p0[r] *= i0; p1[r] *= i1; }
    }
    __syncthreads();   // all logit reads complete before in-place overwrite
    if(tid < 128){
        #pragma unroll
        for(int r = 0; r < 17; r++)
            logit[sm_m*69 + sm_hp*17 + r] =
                (int)((unsigned)f2h(p0[r]) | ((unsigned)f2h(p1[r]) << 16));
    }
    __syncthreads();

    // ---- phase B: out[m][ch] = P @ Vt; packed pair = 1 read feeds 2 heads ----
    f32x4 acc[4][2];
    #pragma unroll
    for(int h = 0; h < 4; h++)
        #pragma unroll
        for(int c = 0; c < 2; c++) acc[h][c] = (f32x4){0.f,0.f,0.f,0.f};

    for(int nc = 0; nc < 16; nc++){
        uint2 sd = *(const uint2*)(&secl[ml*520 + nc*32 + rg*8]);
        #pragma unroll
        for(int hp = 0; hp < 2; hp++){
            const unsigned int* apl = (const unsigned int*)&logit[ml*69 + hp*17];
            unsigned short tlo[8] __attribute__((aligned(16)));
            unsigned short thi[8] __attribute__((aligned(16)));
            #pragma unroll
            for(int j = 0; j < 4; j++){
                unsigned v = apl[(sd.x >> (8*j)) & 255];
                tlo[j] = (unsigned short)v; thi[j] = (unsigned short)(v >> 16);
            }
            #pragma unroll
            for(int j = 0; j < 4; j++){
                unsigned v = apl[(sd.y >> (8*j)) & 255];
                tlo[4+j] = (unsigned short)v; thi[4+j] = (unsigned short)(v >> 16);
            }
            half8 pf0 = *(const half8*)tlo;
            half8 pf1 = *(const half8*)thi;
            #pragma unroll
            for(int c = 0; c < 2; c++){
                half8 vf0 = *(const half8*)(vt + ((size_t)(b*128 + (hp*2  )*32 + c*16 + colm))*512
                                               + nc*32 + rg*8);
                half8 vf1 = *(const half8*)(vt + ((size_t)(b*128 + (hp*2+1)*32 + c*16 + colm))*512
                                               + nc*32 + rg*8);
                acc[hp*2  ][c] = __builtin_amdgcn_mfma_f32_16x16x32_f16(pf0, vf0, acc[hp*2  ][c], 0, 0, 0);
                acc[hp*2+1][c] = __builtin_amdgcn_mfma_f32_16x16x32_f16(pf1, vf1, acc[hp*2+1][c], 0, 0, 0);
            }
        }
    }
    #pragma unroll
    for(int h = 0; h < 4; h++)
        #pragma unroll
        for(int c = 0; c < 2; c++)
            #pragma unroll
            for(int reg = 0; reg < 4; reg++)
                out[((size_t)(b*512 + m0 + w*16 + rg*4 + reg))*128 + h*32 + c*16 + colm]
                    = f2h(acc[h][c][reg]);
}

// ---------------------------------------------------------------------------
extern "C" void kernel_launch(void* const* d_in, const int* in_sizes, int n_in,
                              void* d_out, int out_size, void* d_ws, size_t ws_size,
                              hipStream_t stream){
    const float* x        = (const float*)d_in[0];
    const float* pos      = (const float*)d_in[1];
    const float* t_qkv_w  = (const float*)d_in[2];
    const float* t_proj_w = (const float*)d_in[3];
    const float* t_proj_b = (const float*)d_in[4];
    const float* t_ln_g   = (const float*)d_in[5];
    const float* t_ln_b   = (const float*)d_in[6];
    const float* t_ff_w1  = (const float*)d_in[7];
    const float* t_ff_b1  = (const float*)d_in[8];
    const float* t_ff_w2  = (const float*)d_in[9];
    const float* t_ff_b2  = (const float*)d_in[10];
    const float* assign   = (const float*)d_in[11];
    const unsigned char* s_mask_raw = (const unsigned char*)d_in[12];  // dict order!
    const float* s_q_w    = (const float*)d_in[13];
    const float* s_kv_w   = (const float*)d_in[14];
    const float* s_bias   = (const float*)d_in[15];
    const float* s_proj_w = (const float*)d_in[16];
    const float* s_proj_b = (const float*)d_in[17];
    const float* s_ln_g   = (const float*)d_in[18];
    const float* s_ln_b   = (const float*)d_in[19];
    const float* s_ff_w1  = (const float*)d_in[20];
    const float* s_ff_b1  = (const float*)d_in[21];
    const float* s_ff_w2  = (const float*)d_in[22];
    const float* s_ff_b2  = (const float*)d_in[23];

    float* ws = (float*)d_ws;
    // activation buffers are fp16 but keep the float-unit byte offsets
    // (2x over-allocated) to preserve the proven layout.
    const int CH = (ws_size >= (size_t)168*1024*1024) ? 1 : 4;
    unsigned short* A  = (unsigned short*)ws;
    unsigned short* TS = (unsigned short*)(ws + TOK);
    unsigned short* E  = (unsigned short*)((CH==1) ? (ws + 5*(size_t)TOK) : (ws + TOK));
    unsigned short* SS = (CH==1) ? TS : A;
    unsigned short* Cb = (unsigned short*)d_out;  // fp16 scratch inside f32 d_out
    char*  sb = (char*)(ws + ((CH==1)? 6*(size_t)TOK : 2*(size_t)TOK));
    unsigned char*  sec   = (unsigned char*)sb;              // 262144 B
    unsigned char*  maskn = (unsigned char*)(sb + 823296);   // 8704 B
    unsigned short* wt    = (unsigned short*)(sb + 1048576); // 1572864 B fp16 weights

    const int rows = 49152 / CH;       // M rows per chunk (multiple of 128)
    const int nb   = 96 / CH;          // bt values per spatial chunk

    wprep<<<1024, 256, 0, stream>>>(t_qkv_w, t_proj_w, t_ff_w1, t_ff_w2,
                                    s_q_w, s_kv_w, s_proj_w, s_ff_w1, s_ff_w2, wt);
    normalize_mask<<<1, 256, 0, stream>>>(s_mask_raw, maskn);
    build_sec<<<1024, 256, 0, stream>>>(assign, sec);
    stage0<<<2048, 128, 0, stream>>>(x, pos, A);

    for(int d = 0; d < 2; d++){
        for(int c = 0; c < CH; c++){
            const unsigned short* Ac = A + (size_t)c*rows*128;
            gemm4<false,false,false><<<dim3(3, rows/128), 256, 0, stream>>>(
                Ac, wt + d*49152, nullptr, nullptr, TS, 384, 128);
            tattn<<<rows/48, 256, 0, stream>>>(TS, Cb + (size_t)c*rows*128);
        }
        // fused proj + residual + LayerNorm: vout=A, lnout=Cb
        gemm4ln<<<dim3(1, 384), 256, 0, stream>>>(
            Cb, wt + 98304 + d*16384, t_proj_b + d*128, A, A, Cb,
            t_ln_g + d*128, t_ln_b + d*128, 128);
        for(int c = 0; c < CH; c++){
            unsigned short* Ac = A + (size_t)c*rows*128;
            gemm4<true,true,false><<<dim3(4, rows/128), 256, 0, stream>>>(
                Cb + (size_t)c*rows*128, wt + 131072 + d*65536, t_ff_b1 + d*512,
                nullptr, TS, 512, 128);
            gemm4<true,false,true><<<dim3(1, rows/128), 256, 0, stream>>>(
                TS, wt + 262144 + d*65536, t_ff_b2 + d*128, Ac, Ac, 128, 512);
        }
    }

    t2s<<<24576, 256, 0, stream>>>(A, E);

    for(int d = 0; d < 2; d++){
        gemm4<false,false,false><<<dim3(1,384), 256, 0, stream>>>(
            E, wt + 393216 + d*16384, nullptr, nullptr, Cb, 128, 128);
        for(int c = 0; c < CH; c++){
            unsigned short* Ec = E + (size_t)c*nb*512*128;
            unsigned short* skv_u = SS;                              // nb*512*256 fp16
            unsigned short* att = (unsigned short*)((float*)SS + (size_t)nb*512*128);
            unsigned short* vt  = (unsigned short*)((float*)SS + 2*(size_t)nb*512*128);
            gemm4kv<<<dim3(2, nb*512/128), 256, 0, stream>>>(
                Ec, wt + 425984 + d*32768, skv_u, vt, 256, 128);
            sattn2<<<nb*8, 256, 0, stream>>>(
                Cb + (size_t)c*nb*512*128, skv_u, vt, sec, maskn,
                s_bias + d*68, att);
            // fused sproj + residual + LayerNorm: vout=Ec, lnout=Cb chunk
            gemm4ln<<<dim3(1, nb*512/128), 256, 0, stream>>>(
                att, wt + 491520 + d*16384, s_proj_b + d*128, Ec, Ec,
                Cb + (size_t)c*nb*512*128, s_ln_g + d*128, s_ln_b + d*128, 128);
        }
        for(int c = 0; c < CH; c++){
            unsigned short* Ec = E + (size_t)c*rows*128;
            gemm4<true,true,false><<<dim3(4, rows/128), 256, 0, stream>>>(
                Cb + (size_t)c*rows*128, wt + 524288 + d*65536, s_ff_b1 + d*512,
                nullptr, SS, 512, 128);
            gemm4<true,false,true><<<dim3(1, rows/128), 256, 0, stream>>>(
                SS, wt + 655360 + d*65536, s_ff_b2 + d*128, Ec, Ec, 128, 512);
        }
    }

    finalt<<<2048, 128, 0, stream>>>(E, (float*)d_out);
}